// Round 1
// baseline (219.130 us; speedup 1.0000x reference)
//
#include <hip/hip_runtime.h>

// ---------------- types / helpers ----------------
typedef unsigned short u16;
typedef float f32x4 __attribute__((ext_vector_type(4)));
typedef short bf16x8 __attribute__((ext_vector_type(8)));

__device__ __forceinline__ u16 f2bf(float f) {
    unsigned u = __float_as_uint(f);
    u = (u + 0x7FFFu + ((u >> 16) & 1u)) >> 16;
    return (u16)u;
}

// Problem constants
#define BB 2
#define HH 56
#define CC 256
#define NH 8
#define DK 32
#define SQ 3136          // 56*56
#define HP 62
#define SK 3844          // 62*62
#define VT_STRIDE 3856   // padded row stride for Vt (16B-aligned rows)

// workspace offsets (in u16 units)
#define WS_XPAD 0
#define WS_WT   1968128   // 2*3844*256
#define WS_Q    2164736   // + 3*256*256
#define WS_K    3770368   // + 6272*256
#define WS_VT   5738496   // + 2*3844*256
// total: 5738496 + 512*3856 = 7712768 u16 = ~14.7 MB

// ---------------- kernel 0a: reflect-pad x -> bf16 ----------------
__global__ __launch_bounds__(256) void pad_kernel(const float* __restrict__ x,
                                                  u16* __restrict__ xpad) {
    int gid = blockIdx.x * 256 + threadIdx.x;     // over 7688*64
    int row = gid >> 6;
    int c4  = (gid & 63) << 2;
    int b  = row / SK;
    int sp = row - b * SK;
    int hp = sp / HP;
    int wp = sp - hp * HP;
    int hs = hp - 3; hs = hs < 0 ? -hs : (hs >= HH ? 110 - hs : hs);
    int ws_ = wp - 3; ws_ = ws_ < 0 ? -ws_ : (ws_ >= HH ? 110 - ws_ : ws_);
    const float4 v = *(const float4*)&x[((b * SQ + hs * HH + ws_) << 8) + c4];
    ushort4 o;
    o.x = f2bf(v.x); o.y = f2bf(v.y); o.z = f2bf(v.z); o.w = f2bf(v.w);
    *(ushort4*)&xpad[(row << 8) + c4] = o;
}

// ---------------- kernel 0b: transpose weights -> bf16 [mat][n][k] ----------------
__global__ __launch_bounds__(256) void wtrans_kernel(const float* __restrict__ Wq,
                                                     const float* __restrict__ Wk,
                                                     const float* __restrict__ Wv,
                                                     u16* __restrict__ wt) {
    int gid = blockIdx.x * 256 + threadIdx.x;     // over 3*65536
    int mat = gid >> 16;
    int rem = gid & 65535;
    int k = rem >> 8;
    int n = rem & 255;
    const float* W = (mat == 0) ? Wq : ((mat == 1) ? Wk : Wv);
    wt[(mat << 16) + (n << 8) + k] = f2bf(W[(k << 8) + n]);
}

// ---------------- kernel 1: projections (Q/K/V) via MFMA ----------------
// mode = blockIdx.y: 0 -> Q (M=6272, gather interior of xpad), 1 -> K, 2 -> V (store transposed)
__global__ __launch_bounds__(256) void proj_kernel(const u16* __restrict__ xpad,
                                                   const u16* __restrict__ wt,
                                                   const float* __restrict__ bq,
                                                   const float* __restrict__ bk,
                                                   const float* __restrict__ bv,
                                                   u16* __restrict__ qout,
                                                   u16* __restrict__ kout,
                                                   u16* __restrict__ vtout) {
    int mode  = blockIdx.y;
    int mbase = blockIdx.x * 64;
    int M = (mode == 0) ? (BB * SQ) : (BB * SK);
    if (mbase >= M) return;
    int tid = threadIdx.x;
    int wave = tid >> 6, lane = tid & 63, quad = lane >> 4, l16 = lane & 15;

    int m_a = mbase + wave * 16 + l16;   // A-fragment row (m = lane&15)
    int arow;
    if (mode == 0) {
        int b = m_a / SQ, qq = m_a - b * SQ;
        int hh = qq / HH, ww_ = qq - hh * HH;
        arow = b * SK + (hh + 3) * HP + (ww_ + 3);
    } else {
        arow = m_a < BB * SK ? m_a : (BB * SK - 1);
    }
    const u16* wmat = wt + (mode << 16);
    const float* bias = (mode == 0) ? bq : ((mode == 1) ? bk : bv);

    f32x4 acc[16];
#pragma unroll
    for (int i = 0; i < 16; i++) acc[i] = (f32x4){0.f, 0.f, 0.f, 0.f};

    for (int kk = 0; kk < 256; kk += 32) {
        bf16x8 afrag = *(const bf16x8*)&xpad[(arow << 8) + kk + quad * 8];
#pragma unroll
        for (int nt = 0; nt < 16; nt++) {
            bf16x8 bfrag = *(const bf16x8*)&wmat[((nt * 16 + l16) << 8) + kk + quad * 8];
            acc[nt] = __builtin_amdgcn_mfma_f32_16x16x32_bf16(afrag, bfrag, acc[nt], 0, 0, 0);
        }
    }

    // epilogue: C/D layout row = quad*4+reg, col = lane&15
    int mrow_base = mbase + wave * 16 + quad * 4;
#pragma unroll
    for (int r = 0; r < 4; r++) {
        int m = mrow_base + r;
        if (m >= M) continue;
        int b = 0, kp = 0;
        if (mode == 2) { b = m / SK; kp = m - b * SK; }
#pragma unroll
        for (int nt = 0; nt < 16; nt++) {
            int c = nt * 16 + l16;
            float v = acc[nt][r] + bias[c];
            u16 hv = f2bf(v);
            if (mode == 2) {
                vtout[(b * 256 + c) * VT_STRIDE + kp] = hv;
            } else if (mode == 0) {
                qout[(m << 8) + c] = hv;
            } else {
                kout[(m << 8) + c] = hv;
            }
        }
    }
}

// ---------------- kernel 2: flash attention + epilogue ----------------
// grid: (49 q-tiles, 16 b*h). block: 256 = 4 waves; each wave owns 16 queries.
#define KLDS_STRIDE 40
#define VLDS_STRIDE 136
#define PLDS_STRIDE 136
__global__ __launch_bounds__(256) void attn_kernel(const u16* __restrict__ qb,
                                                   const u16* __restrict__ kb,
                                                   const u16* __restrict__ vtb,
                                                   const float* __restrict__ x,
                                                   const float* __restrict__ gammap,
                                                   float* __restrict__ out) {
    __shared__ __align__(16) u16 K_lds[128 * KLDS_STRIDE];
    __shared__ __align__(16) u16 V_lds[32 * VLDS_STRIDE];
    __shared__ __align__(16) u16 P_lds[4][16 * PLDS_STRIDE];

    int tid = threadIdx.x;
    int wave = tid >> 6, lane = tid & 63, quad = lane >> 4, l16 = lane & 15;
    int bh = blockIdx.y;
    int b = bh >> 3, h = bh & 7;
    int qbase = blockIdx.x * 64 + wave * 16;

    // Q as B-operand: B[k=d][n=query]; lane: n = l16 -> query qbase+l16, k = quad*8+j
    bf16x8 qfrag = *(const bf16x8*)&qb[((b * SQ + qbase + l16) << 8) + h * 32 + quad * 8];

    const u16* kg = kb + ((b * SK) << 8) + h * 32;          // K rows [3844][256], this head's 32 cols
    const u16* vg = vtb + (b * 256 + h * 32) * VT_STRIDE;   // Vt rows [32][3856]

    f32x4 o0 = (f32x4){0.f, 0.f, 0.f, 0.f};
    f32x4 o1 = (f32x4){0.f, 0.f, 0.f, 0.f};
    float m_run = -__builtin_inff();
    float l_run = 0.f;

    for (int kbase = 0; kbase < SK; kbase += 128) {
        // ---- stage K [128][32] and Vt [32][128] into LDS (each thread 2x(16B+16B)) ----
#pragma unroll
        for (int u = tid; u < 512; u += 256) {
            int row = u >> 2, part = u & 3;
            int kglob = kbase + row; if (kglob > SK - 1) kglob = SK - 1;
            uint4 dk_ = *(const uint4*)&kg[(kglob << 8) + part * 8];
            *(uint4*)&K_lds[row * KLDS_STRIDE + part * 8] = dk_;

            int du = u >> 4, c16 = u & 15;
            int gcol = kbase + c16 * 8; if (gcol > VT_STRIDE - 8) gcol = VT_STRIDE - 8;
            uint4 dv = *(const uint4*)&vg[du * VT_STRIDE + gcol];
            *(uint4*)&V_lds[du * VLDS_STRIDE + c16 * 8] = dv;
        }
        __syncthreads();

        // ---- E^T = K * Q^T : D[m=key][n=query] ----
        f32x4 et[8];
#pragma unroll
        for (int t = 0; t < 8; t++) {
            bf16x8 kf = *(const bf16x8*)&K_lds[(t * 16 + l16) * KLDS_STRIDE + quad * 8];
            et[t] = __builtin_amdgcn_mfma_f32_16x16x32_bf16(
                kf, qfrag, (f32x4){0.f, 0.f, 0.f, 0.f}, 0, 0, 0);
        }
        if (kbase + 128 > SK) {
#pragma unroll
            for (int t = 0; t < 8; t++)
#pragma unroll
                for (int r = 0; r < 4; r++)
                    if (kbase + t * 16 + quad * 4 + r >= SK) et[t][r] = -__builtin_inff();
        }

        // ---- online softmax (per-lane query = l16; reduce across quads) ----
        float cm = -__builtin_inff();
#pragma unroll
        for (int t = 0; t < 8; t++)
#pragma unroll
            for (int r = 0; r < 4; r++) cm = fmaxf(cm, et[t][r]);
        cm = fmaxf(cm, __shfl_xor(cm, 16));
        cm = fmaxf(cm, __shfl_xor(cm, 32));
        float m_new = fmaxf(m_run, cm);
        float alpha = __expf(m_run - m_new);
        m_run = m_new;

        float s = 0.f;
#pragma unroll
        for (int t = 0; t < 8; t++)
#pragma unroll
            for (int r = 0; r < 4; r++) {
                float pv = __expf(et[t][r] - m_new);
                et[t][r] = pv;
                s += pv;
            }
        s += __shfl_xor(s, 16);
        s += __shfl_xor(s, 32);
        l_run = l_run * alpha + s;

        // broadcast alpha to O-rows (row = quad*4+reg holds query quad*4+reg)
        float aq[4];
#pragma unroll
        for (int r = 0; r < 4; r++) aq[r] = __shfl(alpha, quad * 4 + r);
#pragma unroll
        for (int r = 0; r < 4; r++) { o0[r] *= aq[r]; o1[r] *= aq[r]; }

        // ---- write P to LDS in [query][key] layout (4 consecutive keys packed) ----
        u16* pl = P_lds[wave];
#pragma unroll
        for (int t = 0; t < 8; t++) {
            ushort4 pk;
            pk.x = f2bf(et[t][0]); pk.y = f2bf(et[t][1]);
            pk.z = f2bf(et[t][2]); pk.w = f2bf(et[t][3]);
            *(ushort4*)&pl[l16 * PLDS_STRIDE + t * 16 + quad * 4] = pk;
        }
        __syncthreads();

        // ---- O += P * V : A[m=q][k=key] from P_lds, B[k=key][n=d] from V_lds ----
#pragma unroll
        for (int ks = 0; ks < 4; ks++) {
            bf16x8 pf = *(const bf16x8*)&pl[l16 * PLDS_STRIDE + ks * 32 + quad * 8];
            bf16x8 v0 = *(const bf16x8*)&V_lds[l16 * VLDS_STRIDE + ks * 32 + quad * 8];
            bf16x8 v1 = *(const bf16x8*)&V_lds[(16 + l16) * VLDS_STRIDE + ks * 32 + quad * 8];
            o0 = __builtin_amdgcn_mfma_f32_16x16x32_bf16(pf, v0, o0, 0, 0, 0);
            o1 = __builtin_amdgcn_mfma_f32_16x16x32_bf16(pf, v1, o1, 0, 0, 0);
        }
        __syncthreads();
    }

    // ---- epilogue: out = gamma * (O / l) + x ----
    float g = gammap[0];
#pragma unroll
    for (int r = 0; r < 4; r++) {
        float lr = __shfl(l_run, quad * 4 + r);
        float linv = 1.f / lr;
        int qglob = qbase + quad * 4 + r;
        int base = ((b * SQ + qglob) << 8) + h * 32;
        out[base + l16]      = g * o0[r] * linv + x[base + l16];
        out[base + 16 + l16] = g * o1[r] * linv + x[base + 16 + l16];
    }
}

// ---------------- launcher ----------------
extern "C" void kernel_launch(void* const* d_in, const int* in_sizes, int n_in,
                              void* d_out, int out_size, void* d_ws, size_t ws_size,
                              hipStream_t stream) {
    const float* x     = (const float*)d_in[0];
    const float* Wq    = (const float*)d_in[1];
    const float* bq    = (const float*)d_in[2];
    const float* Wk    = (const float*)d_in[3];
    const float* bk    = (const float*)d_in[4];
    const float* Wv    = (const float*)d_in[5];
    const float* bv    = (const float*)d_in[6];
    const float* gamma = (const float*)d_in[7];
    float* out = (float*)d_out;

    u16* ws   = (u16*)d_ws;
    u16* xpad = ws + WS_XPAD;
    u16* wt   = ws + WS_WT;
    u16* qbuf = ws + WS_Q;
    u16* kbuf = ws + WS_K;
    u16* vtb  = ws + WS_VT;

    pad_kernel<<<1922, 256, 0, stream>>>(x, xpad);                   // 7688*64 threads
    wtrans_kernel<<<768, 256, 0, stream>>>(Wq, Wk, Wv, wt);          // 3*65536 threads
    proj_kernel<<<dim3(121, 3), 256, 0, stream>>>(xpad, wt, bq, bk, bv, qbuf, kbuf, vtb);
    attn_kernel<<<dim3(49, 16), 256, 0, stream>>>(qbuf, kbuf, vtb, x, gamma, out);
}

// Round 3
// 192.827 us; speedup vs baseline: 1.1364x; 1.1364x over previous
//
#include <hip/hip_runtime.h>

// ---------------- types / helpers ----------------
typedef unsigned short u16;
typedef float f32x4 __attribute__((ext_vector_type(4)));
typedef short bf16x8 __attribute__((ext_vector_type(8)));

__device__ __forceinline__ u16 f2bf(float f) {
    unsigned u = __float_as_uint(f);
    u = (u + 0x7FFFu + ((u >> 16) & 1u)) >> 16;
    return (u16)u;
}

#define LOG2E 1.4426950408889634f

#if __has_builtin(__builtin_amdgcn_exp2f)
__device__ __forceinline__ float exp2_fast(float x) { return __builtin_amdgcn_exp2f(x); }
#else
__device__ __forceinline__ float exp2_fast(float x) { return __expf(x * 0.6931471805599453f); }
#endif

// pack two fp32 -> (bf16(b)<<16)|bf16(a), round-half-up
__device__ __forceinline__ unsigned pack2bf(float a, float b) {
    unsigned ua = __float_as_uint(a) + 0x8000u;
    unsigned ub = __float_as_uint(b) + 0x8000u;
#if __has_builtin(__builtin_amdgcn_perm)
    return __builtin_amdgcn_perm(ub, ua, 0x07060302u);
#else
    return ((ua >> 16) & 0xFFFFu) | (ub & 0xFFFF0000u);
#endif
}

// Problem constants
#define BB 2
#define HH 56
#define CC 256
#define NH 8
#define DK 32
#define SQ 3136          // 56*56
#define HP 62
#define SK 3844          // 62*62
#define VT_STRIDE 3856   // padded row stride for Vt (16B-aligned rows)

// workspace offsets (in u16 units)
#define WS_XPAD 0
#define WS_WT   1968128   // 2*3844*256
#define WS_Q    2164736   // + 3*256*256
#define WS_K    3770368   // + 6272*256
#define WS_VT   5738496   // + 2*3844*256
// total: 5738496 + 512*3856 = 7712768 u16 = ~14.7 MB

// ---------------- kernel 0a: reflect-pad x -> bf16 ----------------
__global__ __launch_bounds__(256) void pad_kernel(const float* __restrict__ x,
                                                  u16* __restrict__ xpad) {
    int gid = blockIdx.x * 256 + threadIdx.x;     // over 7688*64
    int row = gid >> 6;
    int c4  = (gid & 63) << 2;
    int b  = row / SK;
    int sp = row - b * SK;
    int hp = sp / HP;
    int wp = sp - hp * HP;
    int hs = hp - 3; hs = hs < 0 ? -hs : (hs >= HH ? 110 - hs : hs);
    int ws_ = wp - 3; ws_ = ws_ < 0 ? -ws_ : (ws_ >= HH ? 110 - ws_ : ws_);
    const float4 v = *(const float4*)&x[((b * SQ + hs * HH + ws_) << 8) + c4];
    ushort4 o;
    o.x = f2bf(v.x); o.y = f2bf(v.y); o.z = f2bf(v.z); o.w = f2bf(v.w);
    *(ushort4*)&xpad[(row << 8) + c4] = o;
}

// ---------------- kernel 0b: transpose weights -> bf16 [mat][n][k] ----------------
// mat 0 (Wq) is pre-scaled by log2(e) so attention scores are in log2 domain.
__global__ __launch_bounds__(256) void wtrans_kernel(const float* __restrict__ Wq,
                                                     const float* __restrict__ Wk,
                                                     const float* __restrict__ Wv,
                                                     u16* __restrict__ wt) {
    int gid = blockIdx.x * 256 + threadIdx.x;     // over 3*65536
    int mat = gid >> 16;
    int rem = gid & 65535;
    int k = rem >> 8;
    int n = rem & 255;
    const float* W = (mat == 0) ? Wq : ((mat == 1) ? Wk : Wv);
    float val = W[(k << 8) + n];
    if (mat == 0) val *= LOG2E;
    wt[(mat << 16) + (n << 8) + k] = f2bf(val);
}

// ---------------- kernel 1: projections (Q/K/V) via MFMA ----------------
// mode = blockIdx.y: 0 -> Q (M=6272, gather interior of xpad), 1 -> K, 2 -> V (store transposed, paired)
__global__ __launch_bounds__(256) void proj_kernel(const u16* __restrict__ xpad,
                                                   const u16* __restrict__ wt,
                                                   const float* __restrict__ bq,
                                                   const float* __restrict__ bk,
                                                   const float* __restrict__ bv,
                                                   u16* __restrict__ qout,
                                                   u16* __restrict__ kout,
                                                   u16* __restrict__ vtout) {
    int mode  = blockIdx.y;
    int mbase = blockIdx.x * 64;
    int M = (mode == 0) ? (BB * SQ) : (BB * SK);
    if (mbase >= M) return;
    int tid = threadIdx.x;
    int wave = tid >> 6, lane = tid & 63, quad = lane >> 4, l16 = lane & 15;

    int m_a = mbase + wave * 16 + l16;   // A-fragment row (m = lane&15)
    int arow;
    if (mode == 0) {
        int b = m_a / SQ, qq = m_a - b * SQ;
        int hh = qq / HH, ww_ = qq - hh * HH;
        arow = b * SK + (hh + 3) * HP + (ww_ + 3);
    } else {
        arow = m_a < BB * SK ? m_a : (BB * SK - 1);
    }
    const u16* wmat = wt + (mode << 16);
    const float* bias = (mode == 0) ? bq : ((mode == 1) ? bk : bv);
    float bscale = (mode == 0) ? LOG2E : 1.0f;

    f32x4 acc[16];
#pragma unroll
    for (int i = 0; i < 16; i++) acc[i] = (f32x4){0.f, 0.f, 0.f, 0.f};

    for (int kk = 0; kk < 256; kk += 32) {
        bf16x8 afrag = *(const bf16x8*)&xpad[(arow << 8) + kk + quad * 8];
#pragma unroll
        for (int nt = 0; nt < 16; nt++) {
            bf16x8 bfrag = *(const bf16x8*)&wmat[((nt * 16 + l16) << 8) + kk + quad * 8];
            acc[nt] = __builtin_amdgcn_mfma_f32_16x16x32_bf16(afrag, bfrag, acc[nt], 0, 0, 0);
        }
    }

    // epilogue: C/D layout row = quad*4+reg, col = lane&15
    int mrow_base = mbase + wave * 16 + quad * 4;
    if (mode == 2) {
        // Vt: store pairs of consecutive kp as one 4B write (rows r0/r1 and r2/r3
        // are consecutive m => consecutive kp; SK%4==0 so pairs never straddle batch)
#pragma unroll
        for (int nt = 0; nt < 16; nt++) {
            int c = nt * 16 + l16;
            float bvv = bias[c];
#pragma unroll
            for (int p = 0; p < 4; p += 2) {
                int m = mrow_base + p;
                if (m + 1 < M) {
                    int bb = m / SK;
                    int kp = m - bb * SK;
                    unsigned pk = pack2bf(acc[nt][p] + bvv, acc[nt][p + 1] + bvv);
                    *(unsigned*)&vtout[(size_t)(bb * 256 + c) * VT_STRIDE + kp] = pk;
                }
            }
        }
    } else {
#pragma unroll
        for (int r = 0; r < 4; r++) {
            int m = mrow_base + r;
            if (m >= M) continue;
#pragma unroll
            for (int nt = 0; nt < 16; nt++) {
                int c = nt * 16 + l16;
                float v = acc[nt][r] + bias[c] * bscale;
                u16 hv = f2bf(v);
                if (mode == 0) qout[(m << 8) + c] = hv;
                else           kout[(m << 8) + c] = hv;
            }
        }
    }
}

// ---------------- kernel 2: flash attention (fixed m=0) + epilogue ----------------
// grid: (49 q-tiles, 16 b*h). block: 256 = 4 waves; each wave owns 16 queries.
#define KSTR 40
#define VSTR 136
#define PSTR 144
#define NCH 31
__global__ __launch_bounds__(256) void attn_kernel(const u16* __restrict__ qb,
                                                   const u16* __restrict__ kb,
                                                   const u16* __restrict__ vtb,
                                                   const float* __restrict__ x,
                                                   const float* __restrict__ gammap,
                                                   float* __restrict__ out) {
    __shared__ __align__(16) u16 K_lds[128 * KSTR];
    __shared__ __align__(16) u16 V_lds[32 * VSTR];
    __shared__ __align__(16) u16 P_lds[4][16 * PSTR];

    int tid = threadIdx.x;
    int wave = tid >> 6, lane = tid & 63, quad = lane >> 4, l16 = lane & 15;
    int bh = blockIdx.y;
    int b = bh >> 3, h = bh & 7;
    int qbase = blockIdx.x * 64 + wave * 16;

    // Q as B-operand: B[k=d][n=query]; n = l16 -> query qbase+l16, k = quad*8+j
    bf16x8 qfrag = *(const bf16x8*)&qb[((size_t)(b * SQ + qbase + l16) << 8) + h * 32 + quad * 8];

    const u16* kg = kb + ((size_t)(b * SK) << 8) + h * 32;        // K rows [3844][256], head slice
    const u16* vg = vtb + (size_t)(b * 256 + h * 32) * VT_STRIDE; // Vt rows [32][3856]

    // staging roles
    int srow = tid >> 2, spart = tid & 3;   // K rows srow, srow+64 (16B pieces)
    int sdu  = tid >> 4, sc16  = tid & 15;  // Vt rows sdu, sdu+16 (16B col pieces)

    f32x4 o0 = (f32x4){0.f, 0.f, 0.f, 0.f};
    f32x4 o1 = (f32x4){0.f, 0.f, 0.f, 0.f};
    f32x4 o2 = (f32x4){0.f, 0.f, 0.f, 0.f};  // row-sums (l) via ones-column MFMA

    // ones B-fragment: B[k][0]=1, else 0 -> only lanes with l16==0 hold ones
    bf16x8 onesf;
    {
        short ov = (l16 == 0) ? (short)0x3F80 : (short)0;
        onesf = (bf16x8){ov, ov, ov, ov, ov, ov, ov, ov};
    }

    uint4 kr0, kr1, vr0, vr1;
    auto prefetch = [&](int kbase) {
        int g0 = kbase + srow;      if (g0 > SK - 1) g0 = SK - 1;
        int g1 = kbase + srow + 64; if (g1 > SK - 1) g1 = SK - 1;
        kr0 = *(const uint4*)&kg[((size_t)g0 << 8) + spart * 8];
        kr1 = *(const uint4*)&kg[((size_t)g1 << 8) + spart * 8];
        int gc = kbase + sc16 * 8;  if (gc > VT_STRIDE - 8) gc = VT_STRIDE - 8;
        vr0 = *(const uint4*)&vg[(size_t)sdu * VT_STRIDE + gc];
        vr1 = *(const uint4*)&vg[(size_t)(sdu + 16) * VT_STRIDE + gc];
    };
    auto writeK = [&]() {
        *(uint4*)&K_lds[srow * KSTR + spart * 8] = kr0;
        *(uint4*)&K_lds[(srow + 64) * KSTR + spart * 8] = kr1;
    };
    auto writeV = [&]() {
        *(uint4*)&V_lds[sdu * VSTR + sc16 * 8] = vr0;
        *(uint4*)&V_lds[(sdu + 16) * VSTR + sc16 * 8] = vr1;
    };

    prefetch(0);
    writeK(); writeV();
    __syncthreads();
    prefetch(128);

    u16* pl = P_lds[wave];

    for (int ch = 0; ch < NCH; ch++) {
        // ---- E^T = K * Q^T : D[m=key][n=query] ----
        f32x4 et[8];
#pragma unroll
        for (int t = 0; t < 8; t++) {
            bf16x8 kf = *(const bf16x8*)&K_lds[(t * 16 + l16) * KSTR + quad * 8];
            et[t] = __builtin_amdgcn_mfma_f32_16x16x32_bf16(
                kf, qfrag, (f32x4){0.f, 0.f, 0.f, 0.f}, 0, 0, 0);
        }
        if (ch == NCH - 1) {
            int kb0 = ch * 128;
#pragma unroll
            for (int t = 0; t < 8; t++)
#pragma unroll
                for (int r = 0; r < 4; r++)
                    if (kb0 + t * 16 + quad * 4 + r >= SK) et[t][r] = -__builtin_inff();
        }

        // ---- P = 2^score (scores pre-scaled by log2e), pack to bf16, write LDS ----
#pragma unroll
        for (int t = 0; t < 8; t++) {
            unsigned lo = pack2bf(exp2_fast(et[t][0]), exp2_fast(et[t][1]));
            unsigned hi = pack2bf(exp2_fast(et[t][2]), exp2_fast(et[t][3]));
            *(uint2*)&pl[l16 * PSTR + t * 16 + quad * 4] = (uint2){lo, hi};
        }
        __syncthreads();   // A: all QK reads of K_lds done; P visible

        // ---- O += P*V ; l += P*ones ----
#pragma unroll
        for (int ks = 0; ks < 4; ks++) {
            bf16x8 pf = *(const bf16x8*)&pl[l16 * PSTR + ks * 32 + quad * 8];
            bf16x8 v0 = *(const bf16x8*)&V_lds[l16 * VSTR + ks * 32 + quad * 8];
            bf16x8 v1 = *(const bf16x8*)&V_lds[(16 + l16) * VSTR + ks * 32 + quad * 8];
            o0 = __builtin_amdgcn_mfma_f32_16x16x32_bf16(pf, v0, o0, 0, 0, 0);
            o1 = __builtin_amdgcn_mfma_f32_16x16x32_bf16(pf, v1, o1, 0, 0, 0);
            o2 = __builtin_amdgcn_mfma_f32_16x16x32_bf16(pf, onesf, o2, 0, 0, 0);
        }
        bool more = (ch + 1 < NCH);
        if (more) writeK();          // K region free after barrier A
        __syncthreads();             // B: PV done; next K visible
        if (more) {
            writeV();                // V region free after barrier B; visible by next A
            prefetch((ch + 2) * 128);
        }
    }

    // ---- epilogue: out = gamma * (O / l) + x ----
    float g = gammap[0];
#pragma unroll
    for (int r = 0; r < 4; r++) {
        float lr = __shfl(o2[r], quad * 16);   // col 0 of own quad holds row-sum
        float linv = 1.f / lr;
        int qglob = qbase + quad * 4 + r;
        size_t base = ((size_t)(b * SQ + qglob) << 8) + h * 32;
        out[base + l16]      = g * o0[r] * linv + x[base + l16];
        out[base + 16 + l16] = g * o1[r] * linv + x[base + 16 + l16];
    }
}

// ---------------- launcher ----------------
extern "C" void kernel_launch(void* const* d_in, const int* in_sizes, int n_in,
                              void* d_out, int out_size, void* d_ws, size_t ws_size,
                              hipStream_t stream) {
    const float* x     = (const float*)d_in[0];
    const float* Wq    = (const float*)d_in[1];
    const float* bq    = (const float*)d_in[2];
    const float* Wk    = (const float*)d_in[3];
    const float* bk    = (const float*)d_in[4];
    const float* Wv    = (const float*)d_in[5];
    const float* bv    = (const float*)d_in[6];
    const float* gamma = (const float*)d_in[7];
    float* out = (float*)d_out;

    u16* ws   = (u16*)d_ws;
    u16* xpad = ws + WS_XPAD;
    u16* wt   = ws + WS_WT;
    u16* qbuf = ws + WS_Q;
    u16* kbuf = ws + WS_K;
    u16* vtb  = ws + WS_VT;

    pad_kernel<<<1922, 256, 0, stream>>>(x, xpad);                   // 7688*64 threads
    wtrans_kernel<<<768, 256, 0, stream>>>(Wq, Wk, Wv, wt);          // 3*65536 threads
    proj_kernel<<<dim3(121, 3), 256, 0, stream>>>(xpad, wt, bq, bk, bv, qbuf, kbuf, vtb);
    attn_kernel<<<dim3(49, 16), 256, 0, stream>>>(qbuf, kbuf, vtb, x, gamma, out);
}

// Round 4
// 177.867 us; speedup vs baseline: 1.2320x; 1.0841x over previous
//
#include <hip/hip_runtime.h>

// ---------------- types / helpers ----------------
typedef unsigned short u16;
typedef float f32x4 __attribute__((ext_vector_type(4)));
typedef short bf16x8 __attribute__((ext_vector_type(8)));
typedef short bf16x4 __attribute__((ext_vector_type(4)));

__device__ __forceinline__ u16 f2bf(float f) {
    unsigned u = __float_as_uint(f);
    u = (u + 0x7FFFu + ((u >> 16) & 1u)) >> 16;
    return (u16)u;
}

#define LOG2E 1.4426950408889634f

#if __has_builtin(__builtin_amdgcn_exp2f)
__device__ __forceinline__ float exp2_fast(float x) { return __builtin_amdgcn_exp2f(x); }
#else
__device__ __forceinline__ float exp2_fast(float x) { return __expf(x * 0.6931471805599453f); }
#endif

// pack two fp32 -> (bf16(b)<<16)|bf16(a), round-half-up
__device__ __forceinline__ unsigned pack2bf(float a, float b) {
    unsigned ua = __float_as_uint(a) + 0x8000u;
    unsigned ub = __float_as_uint(b) + 0x8000u;
#if __has_builtin(__builtin_amdgcn_perm)
    return __builtin_amdgcn_perm(ub, ua, 0x07060302u);
#else
    return ((ua >> 16) & 0xFFFFu) | (ub & 0xFFFF0000u);
#endif
}

__device__ __forceinline__ bf16x4 bc4(uint2 u) { return __builtin_bit_cast(bf16x4, u); }

// PV MFMA: 16x16x16 bf16 (K=16). A[m=lane&15][k=quad*4+j], B[k=quad*4+j][n=lane&15].
#if __has_builtin(__builtin_amdgcn_mfma_f32_16x16x16bf16_1k)
__device__ __forceinline__ f32x4 pv_mfma(bf16x4 a, bf16x4 b, f32x4 c) {
    return __builtin_amdgcn_mfma_f32_16x16x16bf16_1k(a, b, c, 0, 0, 0);
}
#elif __has_builtin(__builtin_amdgcn_mfma_f32_16x16x16_bf16)
__device__ __forceinline__ f32x4 pv_mfma(bf16x4 a, bf16x4 b, f32x4 c) {
    return __builtin_amdgcn_mfma_f32_16x16x16_bf16(a, b, c, 0, 0, 0);
}
#else
// Exact fallback: 16x16x32 with zero-padded high halves (j>=4 slots are 0 in A,
// so B's j>=4 slots are multiplied by exact zero).
__device__ __forceinline__ f32x4 pv_mfma(bf16x4 a, bf16x4 b, f32x4 c) {
    bf16x8 a8 = {a[0], a[1], a[2], a[3], 0, 0, 0, 0};
    bf16x8 b8 = {b[0], b[1], b[2], b[3], 0, 0, 0, 0};
    return __builtin_amdgcn_mfma_f32_16x16x32_bf16(a8, b8, c, 0, 0, 0);
}
#endif

// Problem constants
#define BB 2
#define HH 56
#define CC 256
#define NH 8
#define DK 32
#define SQ 3136          // 56*56
#define HP 62
#define SK 3844          // 62*62
#define VT_STRIDE 3856   // padded row stride for Vt (16B-aligned rows)

// workspace offsets (in u16 units)
#define WS_XPAD 0
#define WS_WT   1968128   // 2*3844*256
#define WS_Q    2164736   // + 3*256*256
#define WS_K    3770368   // + 6272*256
#define WS_VT   5738496   // + 2*3844*256

// ---------------- kernel 0a: reflect-pad x -> bf16 ----------------
__global__ __launch_bounds__(256) void pad_kernel(const float* __restrict__ x,
                                                  u16* __restrict__ xpad) {
    int gid = blockIdx.x * 256 + threadIdx.x;     // over 7688*64
    int row = gid >> 6;
    int c4  = (gid & 63) << 2;
    int b  = row / SK;
    int sp = row - b * SK;
    int hp = sp / HP;
    int wp = sp - hp * HP;
    int hs = hp - 3; hs = hs < 0 ? -hs : (hs >= HH ? 110 - hs : hs);
    int ws_ = wp - 3; ws_ = ws_ < 0 ? -ws_ : (ws_ >= HH ? 110 - ws_ : ws_);
    const float4 v = *(const float4*)&x[((b * SQ + hs * HH + ws_) << 8) + c4];
    ushort4 o;
    o.x = f2bf(v.x); o.y = f2bf(v.y); o.z = f2bf(v.z); o.w = f2bf(v.w);
    *(ushort4*)&xpad[(row << 8) + c4] = o;
}

// ---------------- kernel 0b: transpose weights -> bf16 [mat][n][k] ----------------
// mat 0 (Wq) is pre-scaled by log2(e) so attention scores are in log2 domain.
__global__ __launch_bounds__(256) void wtrans_kernel(const float* __restrict__ Wq,
                                                     const float* __restrict__ Wk,
                                                     const float* __restrict__ Wv,
                                                     u16* __restrict__ wt) {
    int gid = blockIdx.x * 256 + threadIdx.x;     // over 3*65536
    int mat = gid >> 16;
    int rem = gid & 65535;
    int k = rem >> 8;
    int n = rem & 255;
    const float* W = (mat == 0) ? Wq : ((mat == 1) ? Wk : Wv);
    float val = W[(k << 8) + n];
    if (mat == 0) val *= LOG2E;
    wt[(mat << 16) + (n << 8) + k] = f2bf(val);
}

// ---------------- kernel 1: projections (Q/K/V) via MFMA, W staged in LDS ----------------
#define BSTR 40
__global__ __launch_bounds__(256) void proj_kernel(const u16* __restrict__ xpad,
                                                   const u16* __restrict__ wt,
                                                   const float* __restrict__ bq,
                                                   const float* __restrict__ bk,
                                                   const float* __restrict__ bv,
                                                   u16* __restrict__ qout,
                                                   u16* __restrict__ kout,
                                                   u16* __restrict__ vtout) {
    __shared__ __align__(16) u16 Bl[256 * BSTR];

    int mode  = blockIdx.y;
    int mbase = blockIdx.x * 64;
    int M = (mode == 0) ? (BB * SQ) : (BB * SK);
    if (mbase >= M) return;
    int tid = threadIdx.x;
    int wave = tid >> 6, lane = tid & 63, quad = lane >> 4, l16 = lane & 15;

    int m_a = mbase + wave * 16 + l16;   // A-fragment row (m = lane&15)
    int arow;
    if (mode == 0) {
        int b = m_a / SQ, qq = m_a - b * SQ;
        int hh = qq / HH, ww_ = qq - hh * HH;
        arow = b * SK + (hh + 3) * HP + (ww_ + 3);
    } else {
        arow = m_a < BB * SK ? m_a : (BB * SK - 1);
    }
    const u16* wmat = wt + (mode << 16);
    const float* bias = (mode == 0) ? bq : ((mode == 1) ? bk : bv);
    float bscale = (mode == 0) ? LOG2E : 1.0f;

    f32x4 acc[16];
#pragma unroll
    for (int i = 0; i < 16; i++) acc[i] = (f32x4){0.f, 0.f, 0.f, 0.f};

    uint4 breg[4];
    auto bload = [&](int kk) {
#pragma unroll
        for (int i = 0; i < 4; i++) {
            int j = i * 256 + tid;
            int rrow = j >> 2, p = j & 3;
            breg[i] = *(const uint4*)&wmat[(rrow << 8) + kk + p * 8];
        }
    };

    bload(0);
    for (int s = 0; s < 8; ++s) {
        int kk = s * 32;
#pragma unroll
        for (int i = 0; i < 4; i++) {
            int j = i * 256 + tid;
            int rrow = j >> 2, p = j & 3;
            *(uint4*)&Bl[rrow * BSTR + p * 8] = breg[i];
        }
        __syncthreads();
        if (s < 7) bload(kk + 32);
        bf16x8 afrag = *(const bf16x8*)&xpad[((size_t)arow << 8) + kk + quad * 8];
#pragma unroll
        for (int nt = 0; nt < 16; nt++) {
            bf16x8 bfrag = *(const bf16x8*)&Bl[(nt * 16 + l16) * BSTR + quad * 8];
            acc[nt] = __builtin_amdgcn_mfma_f32_16x16x32_bf16(afrag, bfrag, acc[nt], 0, 0, 0);
        }
        __syncthreads();
    }

    // epilogue: C/D layout row = quad*4+reg, col = lane&15
    int mrow_base = mbase + wave * 16 + quad * 4;
    if (mode == 2) {
#pragma unroll
        for (int nt = 0; nt < 16; nt++) {
            int c = nt * 16 + l16;
            float bvv = bias[c];
#pragma unroll
            for (int p = 0; p < 4; p += 2) {
                int m = mrow_base + p;
                if (m + 1 < M) {
                    int bb = m / SK;
                    int kp = m - bb * SK;
                    unsigned pk = pack2bf(acc[nt][p] + bvv, acc[nt][p + 1] + bvv);
                    *(unsigned*)&vtout[(size_t)(bb * 256 + c) * VT_STRIDE + kp] = pk;
                }
            }
        }
    } else {
#pragma unroll
        for (int r = 0; r < 4; r++) {
            int m = mrow_base + r;
            if (m >= M) continue;
#pragma unroll
            for (int nt = 0; nt < 16; nt++) {
                int c = nt * 16 + l16;
                float v = acc[nt][r] + bias[c] * bscale;
                u16 hv = f2bf(v);
                if (mode == 0) qout[((size_t)m << 8) + c] = hv;
                else           kout[((size_t)m << 8) + c] = hv;
            }
        }
    }
}

// ---------------- kernel 2: flash attention (fixed m=0), key-split waves ----------------
// grid: (49 q-tiles, 16 b*h), 256 thr = 4 waves. Block owns 64 queries.
// wave w: queries qbase + (w&1)*32 .. +31; key-half (w>>1): chunks 0..15 / 16..31.
// P never touches LDS: QK C-layout == PV(16x16x16) A-layout.
#define KSTR 40
#define VSTR 136
__global__ __launch_bounds__(256) void attn_kernel(const u16* __restrict__ qb,
                                                   const u16* __restrict__ kb,
                                                   const u16* __restrict__ vtb,
                                                   const float* __restrict__ x,
                                                   const float* __restrict__ gammap,
                                                   float* __restrict__ out) {
    __shared__ __align__(16) u16 K_lds[2][128 * KSTR];   // [key-half][128 keys x 32 dk]
    __shared__ __align__(16) u16 V_lds[2][32 * VSTR];    // [key-half][32 dk x 128 keys]

    int tid = threadIdx.x;
    int wave = tid >> 6, lane = tid & 63, quad = lane >> 4, l16 = lane & 15;
    int half = wave >> 1, qs = wave & 1;
    int bh = blockIdx.y;
    int b = bh >> 3, h = bh & 7;
    int qsub = blockIdx.x * 64 + qs * 32;

    // Q B-fragments (16x16x32): n = l16 -> query, k = quad*8+j
    bf16x8 qf0 = *(const bf16x8*)&qb[((size_t)(b * SQ + qsub + l16) << 8) + h * 32 + quad * 8];
    bf16x8 qf1 = *(const bf16x8*)&qb[((size_t)(b * SQ + qsub + 16 + l16) << 8) + h * 32 + quad * 8];

    const u16* kg = kb + ((size_t)(b * SK) << 8) + h * 32;
    const u16* vg = vtb + (size_t)(b * 256 + h * 32) * VT_STRIDE;

    int srow = tid >> 2, spart = tid & 3;   // K staging: rows srow, srow+64
    int sdu  = tid >> 4, sc16  = tid & 15;  // V staging: rows sdu, sdu+16

    f32x4 o00{0.f,0.f,0.f,0.f}, o01{0.f,0.f,0.f,0.f};
    f32x4 o10{0.f,0.f,0.f,0.f}, o11{0.f,0.f,0.f,0.f};
    f32x4 l0{0.f,0.f,0.f,0.f},  l1{0.f,0.f,0.f,0.f};

    // ones B-frag (16x16x16): B[k][n=0] = 1 -> lanes with l16==0 hold ones
    short ov = (l16 == 0) ? (short)0x3F80 : (short)0;
    bf16x4 ones4 = {ov, ov, ov, ov};

    uint4 kA0, kA1, kB0, kB1, vA0, vA1, vB0, vB1;
    auto prefetch = [&](int rr) {
        int ka = rr * 128, kbb = (16 + rr) * 128;
        int g;
        g = ka + srow;        if (g > SK - 1) g = SK - 1;
        kA0 = *(const uint4*)&kg[((size_t)g << 8) + spart * 8];
        g = ka + srow + 64;   if (g > SK - 1) g = SK - 1;
        kA1 = *(const uint4*)&kg[((size_t)g << 8) + spart * 8];
        g = kbb + srow;       if (g > SK - 1) g = SK - 1;
        kB0 = *(const uint4*)&kg[((size_t)g << 8) + spart * 8];
        g = kbb + srow + 64;  if (g > SK - 1) g = SK - 1;
        kB1 = *(const uint4*)&kg[((size_t)g << 8) + spart * 8];
        int c = ka + sc16 * 8;  if (c > VT_STRIDE - 8) c = VT_STRIDE - 8;
        vA0 = *(const uint4*)&vg[(size_t)sdu * VT_STRIDE + c];
        vA1 = *(const uint4*)&vg[(size_t)(sdu + 16) * VT_STRIDE + c];
        c = kbb + sc16 * 8;     if (c > VT_STRIDE - 8) c = VT_STRIDE - 8;
        vB0 = *(const uint4*)&vg[(size_t)sdu * VT_STRIDE + c];
        vB1 = *(const uint4*)&vg[(size_t)(sdu + 16) * VT_STRIDE + c];
    };
    auto writeAll = [&]() {
        *(uint4*)&K_lds[0][srow * KSTR + spart * 8] = kA0;
        *(uint4*)&K_lds[0][(srow + 64) * KSTR + spart * 8] = kA1;
        *(uint4*)&K_lds[1][srow * KSTR + spart * 8] = kB0;
        *(uint4*)&K_lds[1][(srow + 64) * KSTR + spart * 8] = kB1;
        *(uint4*)&V_lds[0][sdu * VSTR + sc16 * 8] = vA0;
        *(uint4*)&V_lds[0][(sdu + 16) * VSTR + sc16 * 8] = vA1;
        *(uint4*)&V_lds[1][sdu * VSTR + sc16 * 8] = vB0;
        *(uint4*)&V_lds[1][(sdu + 16) * VSTR + sc16 * 8] = vB1;
    };

    prefetch(0);
    writeAll();
    __syncthreads();
    prefetch(1);

    const u16* Kl = K_lds[half];
    const u16* Vl = V_lds[half];

    for (int r = 0; r < 16; ++r) {
        int ch = half * 16 + r;
        if (ch < 31) {
            bool tail = (ch == 30);
#pragma unroll
            for (int t = 0; t < 8; ++t) {
                bf16x8 kf = *(const bf16x8*)&Kl[(t * 16 + l16) * KSTR + quad * 8];
                f32x4 e0 = __builtin_amdgcn_mfma_f32_16x16x32_bf16(kf, qf0, (f32x4){0.f,0.f,0.f,0.f}, 0, 0, 0);
                f32x4 e1 = __builtin_amdgcn_mfma_f32_16x16x32_bf16(kf, qf1, (f32x4){0.f,0.f,0.f,0.f}, 0, 0, 0);
                float p0[4], p1[4];
                if (tail) {
                    int kb0 = ch * 128 + t * 16 + quad * 4;
#pragma unroll
                    for (int j = 0; j < 4; ++j) {
                        bool valid = (kb0 + j) < SK;
                        p0[j] = valid ? exp2_fast(e0[j]) : 0.f;
                        p1[j] = valid ? exp2_fast(e1[j]) : 0.f;
                    }
                } else {
#pragma unroll
                    for (int j = 0; j < 4; ++j) {
                        p0[j] = exp2_fast(e0[j]);
                        p1[j] = exp2_fast(e1[j]);
                    }
                }
                uint2 u0 = (uint2){pack2bf(p0[0], p0[1]), pack2bf(p0[2], p0[3])};
                uint2 u1 = (uint2){pack2bf(p1[0], p1[1]), pack2bf(p1[2], p1[3])};
                bf16x4 pa0 = bc4(u0), pa1 = bc4(u1);
                uint2 w0 = *(const uint2*)&Vl[l16 * VSTR + t * 16 + quad * 4];
                uint2 w1 = *(const uint2*)&Vl[(16 + l16) * VSTR + t * 16 + quad * 4];
                bf16x4 vb0 = bc4(w0), vb1 = bc4(w1);
                o00 = pv_mfma(pa0, vb0, o00);
                o01 = pv_mfma(pa0, vb1, o01);
                o10 = pv_mfma(pa1, vb0, o10);
                o11 = pv_mfma(pa1, vb1, o11);
                l0  = pv_mfma(pa0, ones4, l0);
                l1  = pv_mfma(pa1, ones4, l1);
            }
        }
        __syncthreads();                 // all reads of this round done
        if (r < 15) writeAll();          // write next round's chunks
        __syncthreads();                 // writes visible
        if (r < 14) prefetch(r + 2);
    }

    // ---- merge key-halves (exact: fixed m=0 partials are plain sums) ----
    float* mg = (float*)&K_lds[0][0];    // 12.3 KB scratch inside 20.5 KB K region
    int slot = (qs * 64 + lane) * 24;
    if (wave >= 2) {
        *(f32x4*)&mg[slot + 0]  = o00;
        *(f32x4*)&mg[slot + 4]  = o01;
        *(f32x4*)&mg[slot + 8]  = o10;
        *(f32x4*)&mg[slot + 12] = o11;
        *(f32x4*)&mg[slot + 16] = l0;
        *(f32x4*)&mg[slot + 20] = l1;
    }
    __syncthreads();
    if (wave < 2) {
        o00 += *(const f32x4*)&mg[slot + 0];
        o01 += *(const f32x4*)&mg[slot + 4];
        o10 += *(const f32x4*)&mg[slot + 8];
        o11 += *(const f32x4*)&mg[slot + 12];
        l0  += *(const f32x4*)&mg[slot + 16];
        l1  += *(const f32x4*)&mg[slot + 20];

        float g = gammap[0];
#pragma unroll
        for (int r2 = 0; r2 < 4; ++r2) {
            float inv0 = 1.f / __shfl(l0[r2], quad * 16);  // col 0 of own quad
            float inv1 = 1.f / __shfl(l1[r2], quad * 16);
            size_t base0 = (size_t)(b * SQ + qsub + quad * 4 + r2) * 256 + h * 32;
            size_t base1 = base0 + (size_t)16 * 256;
            out[base0 + l16]      = g * o00[r2] * inv0 + x[base0 + l16];
            out[base0 + 16 + l16] = g * o01[r2] * inv0 + x[base0 + 16 + l16];
            out[base1 + l16]      = g * o10[r2] * inv1 + x[base1 + l16];
            out[base1 + 16 + l16] = g * o11[r2] * inv1 + x[base1 + 16 + l16];
        }
    }
}

// ---------------- launcher ----------------
extern "C" void kernel_launch(void* const* d_in, const int* in_sizes, int n_in,
                              void* d_out, int out_size, void* d_ws, size_t ws_size,
                              hipStream_t stream) {
    const float* x     = (const float*)d_in[0];
    const float* Wq    = (const float*)d_in[1];
    const float* bq    = (const float*)d_in[2];
    const float* Wk    = (const float*)d_in[3];
    const float* bk    = (const float*)d_in[4];
    const float* Wv    = (const float*)d_in[5];
    const float* bv    = (const float*)d_in[6];
    const float* gamma = (const float*)d_in[7];
    float* out = (float*)d_out;

    u16* ws   = (u16*)d_ws;
    u16* xpad = ws + WS_XPAD;
    u16* wt   = ws + WS_WT;
    u16* qbuf = ws + WS_Q;
    u16* kbuf = ws + WS_K;
    u16* vtb  = ws + WS_VT;

    pad_kernel<<<1922, 256, 0, stream>>>(x, xpad);
    wtrans_kernel<<<768, 256, 0, stream>>>(Wq, Wk, Wv, wt);
    proj_kernel<<<dim3(121, 3), 256, 0, stream>>>(xpad, wt, bq, bk, bv, qbuf, kbuf, vtb);
    attn_kernel<<<dim3(49, 16), 256, 0, stream>>>(qbuf, kbuf, vtb, x, gamma, out);
}

// Round 5
// 174.604 us; speedup vs baseline: 1.2550x; 1.0187x over previous
//
#include <hip/hip_runtime.h>

// ---------------- types / helpers ----------------
typedef unsigned short u16;
typedef float f32x4 __attribute__((ext_vector_type(4)));
typedef short bf16x8 __attribute__((ext_vector_type(8)));
typedef short bf16x4 __attribute__((ext_vector_type(4)));

__device__ __forceinline__ u16 f2bf(float f) {
    unsigned u = __float_as_uint(f);
    u = (u + 0x7FFFu + ((u >> 16) & 1u)) >> 16;
    return (u16)u;
}

#define LOG2E 1.4426950408889634f

#if __has_builtin(__builtin_amdgcn_exp2f)
__device__ __forceinline__ float exp2_fast(float x) { return __builtin_amdgcn_exp2f(x); }
#else
__device__ __forceinline__ float exp2_fast(float x) { return __expf(x * 0.6931471805599453f); }
#endif

// pack two fp32 -> (bf16(b)<<16)|bf16(a), round-half-up
__device__ __forceinline__ unsigned pack2bf(float a, float b) {
    unsigned ua = __float_as_uint(a) + 0x8000u;
    unsigned ub = __float_as_uint(b) + 0x8000u;
#if __has_builtin(__builtin_amdgcn_perm)
    return __builtin_amdgcn_perm(ub, ua, 0x07060302u);
#else
    return ((ua >> 16) & 0xFFFFu) | (ub & 0xFFFF0000u);
#endif
}

__device__ __forceinline__ bf16x4 bc4(uint2 u) { return __builtin_bit_cast(bf16x4, u); }

// PV MFMA: 16x16x16 bf16 (K=16). A[m=lane&15][k=quad*4+j], B[k=quad*4+j][n=lane&15].
#if __has_builtin(__builtin_amdgcn_mfma_f32_16x16x16bf16_1k)
__device__ __forceinline__ f32x4 pv_mfma(bf16x4 a, bf16x4 b, f32x4 c) {
    return __builtin_amdgcn_mfma_f32_16x16x16bf16_1k(a, b, c, 0, 0, 0);
}
#elif __has_builtin(__builtin_amdgcn_mfma_f32_16x16x16_bf16)
__device__ __forceinline__ f32x4 pv_mfma(bf16x4 a, bf16x4 b, f32x4 c) {
    return __builtin_amdgcn_mfma_f32_16x16x16_bf16(a, b, c, 0, 0, 0);
}
#else
// Exact fallback: 16x16x32 with zero-padded high halves.
__device__ __forceinline__ f32x4 pv_mfma(bf16x4 a, bf16x4 b, f32x4 c) {
    bf16x8 a8 = {a[0], a[1], a[2], a[3], 0, 0, 0, 0};
    bf16x8 b8 = {b[0], b[1], b[2], b[3], 0, 0, 0, 0};
    return __builtin_amdgcn_mfma_f32_16x16x32_bf16(a8, b8, c, 0, 0, 0);
}
#endif

// Problem constants
#define BB 2
#define HH 56
#define CC 256
#define NH 8
#define DK 32
#define SQ 3136          // 56*56
#define HP 62
#define SK 3844          // 62*62
#define VT_STRIDE 3856   // padded row stride for Vt (16B-aligned rows)

// workspace offsets (in u16 units)
#define WS_XPAD 0
#define WS_WT   1968128   // 2*3844*256
#define WS_Q    2164736   // + 3*256*256
#define WS_K    3770368   // + 6272*256
#define WS_VT   5738496   // + 2*3844*256

// ---------------- kernel 0a: reflect-pad x -> bf16 ----------------
__global__ __launch_bounds__(256) void pad_kernel(const float* __restrict__ x,
                                                  u16* __restrict__ xpad) {
    int gid = blockIdx.x * 256 + threadIdx.x;     // over 7688*64
    int row = gid >> 6;
    int c4  = (gid & 63) << 2;
    int b  = row / SK;
    int sp = row - b * SK;
    int hp = sp / HP;
    int wp = sp - hp * HP;
    int hs = hp - 3; hs = hs < 0 ? -hs : (hs >= HH ? 110 - hs : hs);
    int ws_ = wp - 3; ws_ = ws_ < 0 ? -ws_ : (ws_ >= HH ? 110 - ws_ : ws_);
    const float4 v = *(const float4*)&x[((b * SQ + hs * HH + ws_) << 8) + c4];
    ushort4 o;
    o.x = f2bf(v.x); o.y = f2bf(v.y); o.z = f2bf(v.z); o.w = f2bf(v.w);
    *(ushort4*)&xpad[(row << 8) + c4] = o;
}

// ---------------- kernel 0b: transpose weights -> bf16 [mat][n][k] ----------------
// mat 0 (Wq) is pre-scaled by log2(e) so attention scores are in log2 domain.
__global__ __launch_bounds__(256) void wtrans_kernel(const float* __restrict__ Wq,
                                                     const float* __restrict__ Wk,
                                                     const float* __restrict__ Wv,
                                                     u16* __restrict__ wt) {
    int gid = blockIdx.x * 256 + threadIdx.x;     // over 3*65536
    int mat = gid >> 16;
    int rem = gid & 65535;
    int k = rem >> 8;
    int n = rem & 255;
    const float* W = (mat == 0) ? Wq : ((mat == 1) ? Wk : Wv);
    float val = W[(k << 8) + n];
    if (mat == 0) val *= LOG2E;
    wt[(mat << 16) + (n << 8) + k] = f2bf(val);
}

// ---------------- kernel 1: projections (Q/K/V) via MFMA, W staged in LDS ----------------
// __launch_bounds__(256,2): acc[16] alone is 64 VGPRs; a tighter cap would spill.
#define BSTR 40
__global__ __launch_bounds__(256, 2) void proj_kernel(const u16* __restrict__ xpad,
                                                   const u16* __restrict__ wt,
                                                   const float* __restrict__ bq,
                                                   const float* __restrict__ bk,
                                                   const float* __restrict__ bv,
                                                   u16* __restrict__ qout,
                                                   u16* __restrict__ kout,
                                                   u16* __restrict__ vtout) {
    __shared__ __align__(16) u16 Bl[256 * BSTR];

    int mode  = blockIdx.y;
    int mbase = blockIdx.x * 64;
    int M = (mode == 0) ? (BB * SQ) : (BB * SK);
    if (mbase >= M) return;
    int tid = threadIdx.x;
    int wave = tid >> 6, lane = tid & 63, quad = lane >> 4, l16 = lane & 15;

    int m_a = mbase + wave * 16 + l16;   // A-fragment row (m = lane&15)
    int arow;
    if (mode == 0) {
        int b = m_a / SQ, qq = m_a - b * SQ;
        int hh = qq / HH, ww_ = qq - hh * HH;
        arow = b * SK + (hh + 3) * HP + (ww_ + 3);
    } else {
        arow = m_a < BB * SK ? m_a : (BB * SK - 1);
    }
    const u16* wmat = wt + (mode << 16);
    const float* bias = (mode == 0) ? bq : ((mode == 1) ? bk : bv);
    float bscale = (mode == 0) ? LOG2E : 1.0f;

    f32x4 acc[16];
#pragma unroll
    for (int i = 0; i < 16; i++) acc[i] = (f32x4){0.f, 0.f, 0.f, 0.f};

    uint4 breg[4];
    auto bload = [&](int kk) {
#pragma unroll
        for (int i = 0; i < 4; i++) {
            int j = i * 256 + tid;
            int rrow = j >> 2, p = j & 3;
            breg[i] = *(const uint4*)&wmat[(rrow << 8) + kk + p * 8];
        }
    };

    bload(0);
    for (int s = 0; s < 8; ++s) {
        int kk = s * 32;
#pragma unroll
        for (int i = 0; i < 4; i++) {
            int j = i * 256 + tid;
            int rrow = j >> 2, p = j & 3;
            *(uint4*)&Bl[rrow * BSTR + p * 8] = breg[i];
        }
        __syncthreads();
        if (s < 7) bload(kk + 32);
        bf16x8 afrag = *(const bf16x8*)&xpad[((size_t)arow << 8) + kk + quad * 8];
#pragma unroll
        for (int nt = 0; nt < 16; nt++) {
            bf16x8 bfrag = *(const bf16x8*)&Bl[(nt * 16 + l16) * BSTR + quad * 8];
            acc[nt] = __builtin_amdgcn_mfma_f32_16x16x32_bf16(afrag, bfrag, acc[nt], 0, 0, 0);
        }
        __syncthreads();
    }

    // epilogue: C/D layout row = quad*4+reg, col = lane&15
    int mrow_base = mbase + wave * 16 + quad * 4;
    if (mode == 2) {
#pragma unroll
        for (int nt = 0; nt < 16; nt++) {
            int c = nt * 16 + l16;
            float bvv = bias[c];
#pragma unroll
            for (int p = 0; p < 4; p += 2) {
                int m = mrow_base + p;
                if (m + 1 < M) {
                    int bb = m / SK;
                    int kp = m - bb * SK;
                    unsigned pk = pack2bf(acc[nt][p] + bvv, acc[nt][p + 1] + bvv);
                    *(unsigned*)&vtout[(size_t)(bb * 256 + c) * VT_STRIDE + kp] = pk;
                }
            }
        }
    } else {
#pragma unroll
        for (int r = 0; r < 4; r++) {
            int m = mrow_base + r;
            if (m >= M) continue;
#pragma unroll
            for (int nt = 0; nt < 16; nt++) {
                int c = nt * 16 + l16;
                float v = acc[nt][r] + bias[c] * bscale;
                u16 hv = f2bf(v);
                if (mode == 0) qout[((size_t)m << 8) + c] = hv;
                else           kout[((size_t)m << 8) + c] = hv;
            }
        }
    }
}

// ---------------- kernel 2: flash attention (fixed m=0), key-split waves ----------------
// grid: (49 q-tiles, 16 b*h), 256 thr = 4 waves. Block owns 64 queries.
// wave w: queries qbase + (w&1)*32 .. +31; key-half (w>>1): chunks 0..15 / 16..31.
// P never touches LDS: QK C-layout == PV(16x16x16) A-layout.
// __launch_bounds__(256,3): grid is 3.06 blocks/CU, so request exactly 3 waves/EU;
// raises the VGPR cap (was 60 with bare (256)) so the t-loop can software-pipeline.
#define KSTR 40
#define VSTR 136
__global__ __launch_bounds__(256, 3) void attn_kernel(const u16* __restrict__ qb,
                                                   const u16* __restrict__ kb,
                                                   const u16* __restrict__ vtb,
                                                   const float* __restrict__ x,
                                                   const float* __restrict__ gammap,
                                                   float* __restrict__ out) {
    __shared__ __align__(16) u16 K_lds[2][128 * KSTR];   // [key-half][128 keys x 32 dk]
    __shared__ __align__(16) u16 V_lds[2][32 * VSTR];    // [key-half][32 dk x 128 keys]

    int tid = threadIdx.x;
    int wave = tid >> 6, lane = tid & 63, quad = lane >> 4, l16 = lane & 15;
    int half = wave >> 1, qs = wave & 1;
    int bh = blockIdx.y;
    int b = bh >> 3, h = bh & 7;
    int qsub = blockIdx.x * 64 + qs * 32;

    // Q B-fragments (16x16x32): n = l16 -> query, k = quad*8+j
    bf16x8 qf0 = *(const bf16x8*)&qb[((size_t)(b * SQ + qsub + l16) << 8) + h * 32 + quad * 8];
    bf16x8 qf1 = *(const bf16x8*)&qb[((size_t)(b * SQ + qsub + 16 + l16) << 8) + h * 32 + quad * 8];

    const u16* kg = kb + ((size_t)(b * SK) << 8) + h * 32;
    const u16* vg = vtb + (size_t)(b * 256 + h * 32) * VT_STRIDE;

    int srow = tid >> 2, spart = tid & 3;   // K staging: rows srow, srow+64
    int sdu  = tid >> 4, sc16  = tid & 15;  // V staging: rows sdu, sdu+16

    f32x4 o00{0.f,0.f,0.f,0.f}, o01{0.f,0.f,0.f,0.f};
    f32x4 o10{0.f,0.f,0.f,0.f}, o11{0.f,0.f,0.f,0.f};
    f32x4 l0{0.f,0.f,0.f,0.f},  l1{0.f,0.f,0.f,0.f};

    // ones B-frag (16x16x16): B[k][n=0] = 1 -> lanes with l16==0 hold ones
    short ov = (l16 == 0) ? (short)0x3F80 : (short)0;
    bf16x4 ones4 = {ov, ov, ov, ov};

    uint4 kA0, kA1, kB0, kB1, vA0, vA1, vB0, vB1;
    auto prefetch = [&](int rr) {
        int ka = rr * 128, kbb = (16 + rr) * 128;
        int g;
        g = ka + srow;        if (g > SK - 1) g = SK - 1;
        kA0 = *(const uint4*)&kg[((size_t)g << 8) + spart * 8];
        g = ka + srow + 64;   if (g > SK - 1) g = SK - 1;
        kA1 = *(const uint4*)&kg[((size_t)g << 8) + spart * 8];
        g = kbb + srow;       if (g > SK - 1) g = SK - 1;
        kB0 = *(const uint4*)&kg[((size_t)g << 8) + spart * 8];
        g = kbb + srow + 64;  if (g > SK - 1) g = SK - 1;
        kB1 = *(const uint4*)&kg[((size_t)g << 8) + spart * 8];
        int c = ka + sc16 * 8;  if (c > VT_STRIDE - 8) c = VT_STRIDE - 8;
        vA0 = *(const uint4*)&vg[(size_t)sdu * VT_STRIDE + c];
        vA1 = *(const uint4*)&vg[(size_t)(sdu + 16) * VT_STRIDE + c];
        c = kbb + sc16 * 8;     if (c > VT_STRIDE - 8) c = VT_STRIDE - 8;
        vB0 = *(const uint4*)&vg[(size_t)sdu * VT_STRIDE + c];
        vB1 = *(const uint4*)&vg[(size_t)(sdu + 16) * VT_STRIDE + c];
    };
    auto writeAll = [&]() {
        *(uint4*)&K_lds[0][srow * KSTR + spart * 8] = kA0;
        *(uint4*)&K_lds[0][(srow + 64) * KSTR + spart * 8] = kA1;
        *(uint4*)&K_lds[1][srow * KSTR + spart * 8] = kB0;
        *(uint4*)&K_lds[1][(srow + 64) * KSTR + spart * 8] = kB1;
        *(uint4*)&V_lds[0][sdu * VSTR + sc16 * 8] = vA0;
        *(uint4*)&V_lds[0][(sdu + 16) * VSTR + sc16 * 8] = vA1;
        *(uint4*)&V_lds[1][sdu * VSTR + sc16 * 8] = vB0;
        *(uint4*)&V_lds[1][(sdu + 16) * VSTR + sc16 * 8] = vB1;
    };

    prefetch(0);
    writeAll();
    __syncthreads();
    prefetch(1);

    const u16* Kl = K_lds[half];
    const u16* Vl = V_lds[half];

    for (int r = 0; r < 16; ++r) {
        int ch = half * 16 + r;
        if (ch < 31) {
            bool tail = (ch == 30);
#pragma unroll
            for (int t = 0; t < 8; ++t) {
                bf16x8 kf = *(const bf16x8*)&Kl[(t * 16 + l16) * KSTR + quad * 8];
                f32x4 e0 = __builtin_amdgcn_mfma_f32_16x16x32_bf16(kf, qf0, (f32x4){0.f,0.f,0.f,0.f}, 0, 0, 0);
                f32x4 e1 = __builtin_amdgcn_mfma_f32_16x16x32_bf16(kf, qf1, (f32x4){0.f,0.f,0.f,0.f}, 0, 0, 0);
                float p0[4], p1[4];
                if (tail) {
                    int kb0 = ch * 128 + t * 16 + quad * 4;
#pragma unroll
                    for (int j = 0; j < 4; ++j) {
                        bool valid = (kb0 + j) < SK;
                        p0[j] = valid ? exp2_fast(e0[j]) : 0.f;
                        p1[j] = valid ? exp2_fast(e1[j]) : 0.f;
                    }
                } else {
#pragma unroll
                    for (int j = 0; j < 4; ++j) {
                        p0[j] = exp2_fast(e0[j]);
                        p1[j] = exp2_fast(e1[j]);
                    }
                }
                uint2 u0 = (uint2){pack2bf(p0[0], p0[1]), pack2bf(p0[2], p0[3])};
                uint2 u1 = (uint2){pack2bf(p1[0], p1[1]), pack2bf(p1[2], p1[3])};
                bf16x4 pa0 = bc4(u0), pa1 = bc4(u1);
                uint2 w0 = *(const uint2*)&Vl[l16 * VSTR + t * 16 + quad * 4];
                uint2 w1 = *(const uint2*)&Vl[(16 + l16) * VSTR + t * 16 + quad * 4];
                bf16x4 vb0 = bc4(w0), vb1 = bc4(w1);
                o00 = pv_mfma(pa0, vb0, o00);
                o01 = pv_mfma(pa0, vb1, o01);
                o10 = pv_mfma(pa1, vb0, o10);
                o11 = pv_mfma(pa1, vb1, o11);
                l0  = pv_mfma(pa0, ones4, l0);
                l1  = pv_mfma(pa1, ones4, l1);
            }
        }
        __syncthreads();                 // all reads of this round done
        if (r < 15) writeAll();          // write next round's chunks
        __syncthreads();                 // writes visible
        if (r < 14) prefetch(r + 2);
    }

    // ---- merge key-halves (exact: fixed m=0 partials are plain sums) ----
    float* mg = (float*)&K_lds[0][0];    // 12.3 KB scratch inside 20.5 KB K region
    int slot = (qs * 64 + lane) * 24;
    if (wave >= 2) {
        *(f32x4*)&mg[slot + 0]  = o00;
        *(f32x4*)&mg[slot + 4]  = o01;
        *(f32x4*)&mg[slot + 8]  = o10;
        *(f32x4*)&mg[slot + 12] = o11;
        *(f32x4*)&mg[slot + 16] = l0;
        *(f32x4*)&mg[slot + 20] = l1;
    }
    __syncthreads();
    if (wave < 2) {
        o00 += *(const f32x4*)&mg[slot + 0];
        o01 += *(const f32x4*)&mg[slot + 4];
        o10 += *(const f32x4*)&mg[slot + 8];
        o11 += *(const f32x4*)&mg[slot + 12];
        l0  += *(const f32x4*)&mg[slot + 16];
        l1  += *(const f32x4*)&mg[slot + 20];

        float g = gammap[0];
#pragma unroll
        for (int r2 = 0; r2 < 4; ++r2) {
            float inv0 = 1.f / __shfl(l0[r2], quad * 16);  // col 0 of own quad
            float inv1 = 1.f / __shfl(l1[r2], quad * 16);
            size_t base0 = (size_t)(b * SQ + qsub + quad * 4 + r2) * 256 + h * 32;
            size_t base1 = base0 + (size_t)16 * 256;
            out[base0 + l16]      = g * o00[r2] * inv0 + x[base0 + l16];
            out[base0 + 16 + l16] = g * o01[r2] * inv0 + x[base0 + 16 + l16];
            out[base1 + l16]      = g * o10[r2] * inv1 + x[base1 + l16];
            out[base1 + 16 + l16] = g * o11[r2] * inv1 + x[base1 + 16 + l16];
        }
    }
}

// ---------------- launcher ----------------
extern "C" void kernel_launch(void* const* d_in, const int* in_sizes, int n_in,
                              void* d_out, int out_size, void* d_ws, size_t ws_size,
                              hipStream_t stream) {
    const float* x     = (const float*)d_in[0];
    const float* Wq    = (const float*)d_in[1];
    const float* bq    = (const float*)d_in[2];
    const float* Wk    = (const float*)d_in[3];
    const float* bk    = (const float*)d_in[4];
    const float* Wv    = (const float*)d_in[5];
    const float* bv    = (const float*)d_in[6];
    const float* gamma = (const float*)d_in[7];
    float* out = (float*)d_out;

    u16* ws   = (u16*)d_ws;
    u16* xpad = ws + WS_XPAD;
    u16* wt   = ws + WS_WT;
    u16* qbuf = ws + WS_Q;
    u16* kbuf = ws + WS_K;
    u16* vtb  = ws + WS_VT;

    pad_kernel<<<1922, 256, 0, stream>>>(x, xpad);
    wtrans_kernel<<<768, 256, 0, stream>>>(Wq, Wk, Wv, wt);
    proj_kernel<<<dim3(121, 3), 256, 0, stream>>>(xpad, wt, bq, bk, bv, qbuf, kbuf, vtb);
    attn_kernel<<<dim3(49, 16), 256, 0, stream>>>(qbuf, kbuf, vtb, x, gamma, out);
}